// Round 20
// baseline (203.952 us; speedup 1.0000x reference)
//
#include <hip/hip_runtime.h>

// BayesianMambaBlock on MI355X (gfx950).
// LN -> fused (in|gate) GEMM [BM=128,BK=128] -> conv+silu -> S GEMM [BM=128,BK=128] (fused u) ->
// abcd GEMM split-K4 + combine -> chunked scan (bf16 state, f32x4 LDS reads, phase3 fused gate) ->
// out GEMM [BM=64,BK=64] (+resid, f32).
// gemm_bt<MODE,BM,BK>: tile BMx128, wave tile 32x64, 2 LDS buffers, vmcnt(0)+s_barrier per K-tile
// with next-tile stage issued one compute-phase ahead, setprio, CPR-chunk/row XOR LDS swizzle,
// XCD-aware block swizzle.

typedef unsigned short u16;
using short8 = __attribute__((ext_vector_type(8))) short;
using f32x4  = __attribute__((ext_vector_type(4))) float;

#define BATCH 2
#define SEQ   2048
#define DM    768
#define DI    1536
#define NIG   (2*DI)        // fused in+gate width 3072
#define NST   16
#define LCH   64
#define NCH   32
#define NTOK  (BATCH*SEQ)   // 4096

__device__ __forceinline__ u16 f2b(float x) {
  unsigned u = __float_as_uint(x);
  u += 0x7FFFu + ((u >> 16) & 1u);   // round-to-nearest-even bf16
  return (u16)(u >> 16);
}
__device__ __forceinline__ float b2f(u16 v) { return __uint_as_float((unsigned)v << 16); }
__device__ __forceinline__ float sigmoidf_(float x) { return 1.f / (1.f + expf(-x)); }
__device__ __forceinline__ float siluf_(float x) { return x / (1.f + expf(-x)); }

// ---------------- one-shot weight prep: all casts in a single launch ----------------
#define N_IG   (NIG * DM / 4)
#define N_WS   (DI * DI / 4)
#define N_WO   (DM * DI / 4)
#define N_WAB  (64 * DI / 4)
#define N_CAST (N_IG + N_WS + N_WO + N_WAB + NIG + 64)

__global__ __launch_bounds__(256) void cast_all(
    const float* __restrict__ Wi, const float* __restrict__ Wg,
    const float* __restrict__ bi, const float* __restrict__ bg,
    const float* __restrict__ WS, const float* __restrict__ WO,
    const float* __restrict__ WA, const float* __restrict__ Wdt,
    const float* __restrict__ WB, const float* __restrict__ WC,
    const float* __restrict__ bA, const float* __restrict__ bdt,
    const float* __restrict__ bB, const float* __restrict__ bC,
    u16* __restrict__ Wigb, float* __restrict__ biasig,
    u16* __restrict__ WSb, u16* __restrict__ Woutb,
    u16* __restrict__ Wabcd, float* __restrict__ bias64) {
  int i = blockIdx.x * 256 + threadIdx.x;
  if (i < N_IG) {
    int i4 = i * 4, r = i4 / DM, c = i4 % DM;
    const float* src = (r < DI) ? Wi + (size_t)r * DM + c : Wg + (size_t)(r - DI) * DM + c;
    float4 v = *(const float4*)src;
    ushort4 o; o.x = f2b(v.x); o.y = f2b(v.y); o.z = f2b(v.z); o.w = f2b(v.w);
    ((ushort4*)Wigb)[i] = o;
  } else if (i < N_IG + N_WS) {
    int j = i - N_IG;
    float4 v = ((const float4*)WS)[j];
    ushort4 o; o.x = f2b(v.x); o.y = f2b(v.y); o.z = f2b(v.z); o.w = f2b(v.w);
    ((ushort4*)WSb)[j] = o;
  } else if (i < N_IG + N_WS + N_WO) {
    int j = i - N_IG - N_WS;
    float4 v = ((const float4*)WO)[j];
    ushort4 o; o.x = f2b(v.x); o.y = f2b(v.y); o.z = f2b(v.z); o.w = f2b(v.w);
    ((ushort4*)Woutb)[j] = o;
  } else if (i < N_IG + N_WS + N_WO + N_WAB) {
    int j = i - N_IG - N_WS - N_WO;
    int i4 = j * 4, r = i4 / DI, c = i4 % DI;
    const float* src = (r < 16) ? WA + (size_t)r * DI
                     : (r < 32) ? Wdt + (size_t)(r - 16) * DI
                     : (r < 48) ? WB + (size_t)(r - 32) * DI
                                : WC + (size_t)(r - 48) * DI;
    float4 v = *(const float4*)(src + c);
    ushort4 o; o.x = f2b(v.x); o.y = f2b(v.y); o.z = f2b(v.z); o.w = f2b(v.w);
    ((ushort4*)Wabcd)[j] = o;
  } else if (i < N_IG + N_WS + N_WO + N_WAB + NIG) {
    int j = i - N_IG - N_WS - N_WO - N_WAB;
    biasig[j] = (j < DI) ? bi[j] : bg[j - DI];
  } else if (i < N_CAST) {
    int j = i - N_IG - N_WS - N_WO - N_WAB - NIG;
    bias64[j] = (j < 16) ? bA[j] : (j < 32) ? bdt[j - 16] : (j < 48) ? bB[j - 32] : bC[j - 48];
  }
}

// ---------------- LayerNorm -> bf16 ----------------
__global__ __launch_bounds__(256) void ln_kernel(const float* __restrict__ x, const float* __restrict__ g,
                                                 const float* __restrict__ bb, u16* __restrict__ xn) {
  int m = blockIdx.x, tid = threadIdx.x;
  const float* xr = x + (size_t)m * DM;
  float v0 = xr[tid], v1 = xr[tid + 256], v2 = xr[tid + 512];
  float s  = v0 + v1 + v2;
  float s2 = fmaf(v0, v0, fmaf(v1, v1, v2 * v2));
  #pragma unroll
  for (int off = 32; off > 0; off >>= 1) { s += __shfl_down(s, off); s2 += __shfl_down(s2, off); }
  __shared__ float sh[8];
  int wave = tid >> 6, lane = tid & 63;
  if (lane == 0) { sh[wave] = s; sh[4 + wave] = s2; }
  __syncthreads();
  float S1 = sh[0] + sh[1] + sh[2] + sh[3];
  float S2 = sh[4] + sh[5] + sh[6] + sh[7];
  float mu = S1 * (1.f / DM);
  float var = S2 * (1.f / DM) - mu * mu;
  float rs = rsqrtf(var + 1e-5f);
  u16* o = xn + (size_t)m * DM;
  o[tid]       = f2b((v0 - mu) * rs * g[tid]       + bb[tid]);
  o[tid + 256] = f2b((v1 - mu) * rs * g[tid + 256] + bb[tid + 256]);
  o[tid + 512] = f2b((v2 - mu) * rs * g[tid + 512] + bb[tid + 512]);
}

__device__ __forceinline__ void gll16(const void* g, void* l) {
  __builtin_amdgcn_global_load_lds((const __attribute__((address_space(1))) void*)g,
                                   (__attribute__((address_space(3))) void*)l, 16, 0, 0);
}

// ---------------- bf16 MFMA NT-GEMM: acc = A[M][K] * B[N][K]^T + bias ----------------
// BM=128: 512 thr/8 waves; BM=64: 256 thr/4 waves. Tile BMx128, wave tile 32x64, template BK.
// 2 LDS buffers; per K-tile: {vmcnt(0); s_barrier; STAGE(t+1); COMPUTE(t)}.
// Staging: CPR=BK/8 chunks/row; chunk c: row=c/CPR, slot c%CPR holds global k-octet
// (c%CPR)^(row%CPR). Read: k-octet q at slot q^(row%CPR).
// MODE 0: C f32 = acc + bias + aux(resid f32); MODE 1: Cb = bf16(b2f(auxb)*sigmoid(acc+bias));
// MODE 2: Cb = bf16(acc+bias)
template <int MODE, int BM, int BK>
__global__ __launch_bounds__(BM == 128 ? 512 : 256) void gemm_bt(
    const u16* __restrict__ A, const u16* __restrict__ B,
    const float* __restrict__ bias, const float* __restrict__ aux,
    const u16* __restrict__ auxb,
    float* __restrict__ C, u16* __restrict__ Cb,
    int M, int N, int K) {
  constexpr int NT   = (BM == 128 ? 512 : 256);
  constexpr int CPR  = BK / 8;           // 16B chunks per row
  constexpr int CM   = CPR - 1;
  constexpr int AU   = BM * CPR / NT;    // A staging units
  constexpr int BU   = 128 * CPR / NT;   // B staging units
  constexpr int RST  = NT / CPR;         // rows per unit (multiple of CPR)
  constexpr int NKK  = BK / 32;          // k-subtiles per K-tile
  __shared__ __align__(16) u16 As[2][BM * BK];
  __shared__ __align__(16) u16 Bs[2][128 * BK];
  const int tid = threadIdx.x, wave = tid >> 6, lane = tid & 63;

  // XCD-aware bijective swizzle (nwg % 8 == 0 for all our grids)
  const int nbx = gridDim.x, nwg = nbx * gridDim.y;
  const int orig = blockIdx.y * nbx + blockIdx.x;
  const int cpx = nwg >> 3;
  const int swz = (orig & 7) * cpx + (orig >> 3);
  const int m0 = (swz / nbx) * BM, n0 = (swz % nbx) * 128;

  const int wm = (wave >> 1) * 32, wn = (wave & 1) * 64;
  const int fr = lane & 15, fq = lane >> 4;
  f32x4 acc[2][4] = {};

  // staging base for chunk c = tid: row = tid/CPR, k-octet (tid%CPR)^(row%CPR)
  const int srow = tid / CPR;
  const u16* Ag0 = A + (size_t)(m0 + srow) * K + (((tid & CM) ^ (srow & CM))) * 8;
  const u16* Bg0 = B + (size_t)(n0 + srow) * K + (((tid & CM) ^ (srow & CM))) * 8;
  const int lbase = (wave * 64) * 8;   // wave-uniform; HW adds lane*16B
  const int lstep = NT * 8;            // u16 per unit

  // ds_read offsets (u16): row r, k-octet q = kk*4+fq at slot q^(r&CM)
  int offA[NKK][2], offB[NKK][4];
  #pragma unroll
  for (int kk = 0; kk < NKK; ++kk) {
    #pragma unroll
    for (int i = 0; i < 2; ++i) {
      int ra = wm + i * 16 + fr;
      offA[kk][i] = ra * BK + (((kk * 4 + fq) ^ (ra & CM))) * 8;
    }
    #pragma unroll
    for (int i = 0; i < 4; ++i) {
      int rb = wn + i * 16 + fr;
      offB[kk][i] = rb * BK + (((kk * 4 + fq) ^ (rb & CM))) * 8;
    }
  }

  const int nk = K / BK;

#define STAGE_BT(tt) { const int bb_ = (tt) & 1; const int ko_ = (tt) * BK; \
    _Pragma("unroll") for (int u = 0; u < AU; ++u) \
      gll16(Ag0 + (size_t)u * RST * K + ko_, (u16*)As[bb_] + u * lstep + lbase); \
    _Pragma("unroll") for (int u = 0; u < BU; ++u) \
      gll16(Bg0 + (size_t)u * RST * K + ko_, (u16*)Bs[bb_] + u * lstep + lbase); }
#define COMPUTE_BT(tt) { const u16* as_ = As[(tt) & 1]; const u16* bs_ = Bs[(tt) & 1]; \
    _Pragma("unroll") for (int kk = 0; kk < NKK; ++kk) { \
      short8 av[2], bv[4]; \
      _Pragma("unroll") for (int i = 0; i < 2; ++i) av[i] = *(const short8*)(as_ + offA[kk][i]); \
      _Pragma("unroll") for (int i = 0; i < 4; ++i) bv[i] = *(const short8*)(bs_ + offB[kk][i]); \
      __builtin_amdgcn_s_setprio(1); \
      _Pragma("unroll") for (int mi = 0; mi < 2; ++mi) \
        _Pragma("unroll") for (int ni = 0; ni < 4; ++ni) \
          acc[mi][ni] = __builtin_amdgcn_mfma_f32_16x16x32_bf16(av[mi], bv[ni], acc[mi][ni], 0, 0, 0); \
      __builtin_amdgcn_s_setprio(0); } }

  STAGE_BT(0);
  for (int t = 0; t < nk; ++t) {
    asm volatile("s_waitcnt vmcnt(0)" ::: "memory");   // tile t landed (issued 1 compute phase ago)
    __builtin_amdgcn_s_barrier();                      // publishes tile t; retires reads of buf (t+1)&1
    if (t + 1 < nk) STAGE_BT(t + 1);
    COMPUTE_BT(t);
  }
#undef STAGE_BT
#undef COMPUTE_BT

  #pragma unroll
  for (int ni = 0; ni < 4; ++ni) {
    int col = n0 + wn + ni * 16 + fr;
    float bv_ = bias[col];
    #pragma unroll
    for (int mi = 0; mi < 2; ++mi) {
      int row = m0 + wm + mi * 16 + fq * 4;
      #pragma unroll
      for (int j = 0; j < 4; ++j) {
        size_t off = (size_t)(row + j) * N + col;
        float z = acc[mi][ni][j] + bv_;
        if (MODE == 0) {
          C[off] = z + aux[off];
        } else if (MODE == 1) {
          Cb[off] = f2b(b2f(auxb[off]) * sigmoidf_(z));
        } else {
          Cb[off] = f2b(z);
        }
      }
    }
  }
}

// ---------------- abcd GEMM split-K: Zp[ks] = ub[M][Kq] * Wabcd[64][Kq]^T ----------------
__global__ __launch_bounds__(256) void gemm_abcd(const u16* __restrict__ A, const u16* __restrict__ B,
                                                 float* __restrict__ Zp, int M, int K) {
  __shared__ __align__(16) u16 As[2][64 * 64];
  __shared__ __align__(16) u16 Bs[2][64 * 64];
  const int tid = threadIdx.x, wave = tid >> 6, lane = tid & 63;
  const int m0 = blockIdx.x * 64;
  const int ks = blockIdx.y;
  const int Kq = K >> 2;            // 384
  const int kbase = ks * Kq;
  const int wm = wave * 16;
  const int fr = lane & 15, fq = lane >> 4;
  f32x4 acc[4] = {};

  const int c0 = tid, c1 = tid + 256;
  const u16* Ag0 = A + (size_t)(m0 + (c0 >> 3)) * K + kbase + ((c0 & 7) ^ ((c0 >> 3) & 7)) * 8;
  const u16* Ag1 = A + (size_t)(m0 + (c1 >> 3)) * K + kbase + ((c1 & 7) ^ ((c1 >> 3) & 7)) * 8;
  const u16* Bg0 = B + (size_t)(c0 >> 3) * K + kbase + ((c0 & 7) ^ ((c0 >> 3) & 7)) * 8;
  const u16* Bg1 = B + (size_t)(c1 >> 3) * K + kbase + ((c1 & 7) ^ ((c1 >> 3) & 7)) * 8;
  const int lo0 = (wave * 64) * 8;
  const int lo1 = (256 + wave * 64) * 8;

  int offAv[2], offBv[2][4];
  {
    int r = wm + fr;
    #pragma unroll
    for (int kk = 0; kk < 2; ++kk) offAv[kk] = r * 64 + ((kk * 4 + fq) ^ (r & 7)) * 8;
    #pragma unroll
    for (int i = 0; i < 4; ++i) {
      int rb = i * 16 + fr;
      #pragma unroll
      for (int kk = 0; kk < 2; ++kk) offBv[kk][i] = rb * 64 + ((kk * 4 + fq) ^ (rb & 7)) * 8;
    }
  }

  const int nk = Kq >> 6;   // 6
  gll16(Ag0, (u16*)As[0] + lo0);
  gll16(Ag1, (u16*)As[0] + lo1);
  gll16(Bg0, (u16*)Bs[0] + lo0);
  gll16(Bg1, (u16*)Bs[0] + lo1);

  for (int t = 0; t < nk; ++t) {
    __syncthreads();
    if (t + 1 < nk) {
      int ko = (t + 1) * 64;
      gll16(Ag0 + ko, (u16*)As[(t + 1) & 1] + lo0);
      gll16(Ag1 + ko, (u16*)As[(t + 1) & 1] + lo1);
      gll16(Bg0 + ko, (u16*)Bs[(t + 1) & 1] + lo0);
      gll16(Bg1 + ko, (u16*)Bs[(t + 1) & 1] + lo1);
    }
    const u16* as = As[t & 1];
    const u16* bs = Bs[t & 1];
    #pragma unroll
    for (int kk = 0; kk < 2; ++kk) {
      short8 av = *(const short8*)(as + offAv[kk]);
      short8 bv[4];
      #pragma unroll
      for (int i = 0; i < 4; ++i) bv[i] = *(const short8*)(bs + offBv[kk][i]);
      #pragma unroll
      for (int ni = 0; ni < 4; ++ni)
        acc[ni] = __builtin_amdgcn_mfma_f32_16x16x32_bf16(av, bv[ni], acc[ni], 0, 0, 0);
    }
  }

  float* zp = Zp + (size_t)ks * M * 64;
  #pragma unroll
  for (int ni = 0; ni < 4; ++ni) {
    int col = ni * 16 + fr;
    #pragma unroll
    for (int j = 0; j < 4; ++j) {
      int row = m0 + wm + fq * 4 + j;
      zp[(size_t)row * 64 + col] = acc[ni][j];
    }
  }
}

// combine split-K partials; fused dec/Bm/Cm epilogue
__global__ __launch_bounds__(256) void abcd_combine(const float* __restrict__ Zp, const float* __restrict__ bias64,
                                                    float* __restrict__ dec, float* __restrict__ Bm,
                                                    float* __restrict__ Cm, int M) {
  int idx = blockIdx.x * 256 + threadIdx.x;  // < M*16
  int row = idx >> 4, n = idx & 15;
  float zA = bias64[n], zDt = bias64[16 + n], zB = bias64[32 + n], zC = bias64[48 + n];
  #pragma unroll
  for (int ks = 0; ks < 4; ++ks) {
    const float* zp = Zp + ((size_t)ks * M + row) * 64;
    zA += zp[n]; zDt += zp[16 + n]; zB += zp[32 + n]; zC += zp[48 + n];
  }
  size_t o = (size_t)row * NST + n;
  dec[o] = expf(-expf(zA + zDt));
  Bm[o] = zB;
  Cm[o] = zC;
}

// ---------------- depthwise causal conv (k=4) + bias + silu; short8-vectorized ----------------
__global__ __launch_bounds__(256) void conv_silu(const u16* __restrict__ xpg, const float* __restrict__ cw,
                                                 const float* __restrict__ cb, u16* __restrict__ xab) {
  int idx = blockIdx.x * 256 + threadIdx.x;   // < NTOK*DI/8
  int d8 = idx % (DI / 8);
  int token = idx / (DI / 8);
  int t = token % SEQ;
  int d0 = d8 * 8;
  const short8* xv = (const short8*)(xpg + (size_t)token * NIG + d0);
  short8 z8 = {0, 0, 0, 0, 0, 0, 0, 0};
  short8 x3 = (t >= 3) ? xv[-3 * (NIG / 8)] : z8;
  short8 x2 = (t >= 2) ? xv[-2 * (NIG / 8)] : z8;
  short8 x1 = (t >= 1) ? xv[-1 * (NIG / 8)] : z8;
  short8 x0 = xv[0];
  const float4* cw4 = (const float4*)cw;
  float4 cbl = ((const float4*)cb)[d8 * 2], cbh = ((const float4*)cb)[d8 * 2 + 1];
  float cbv[8] = {cbl.x, cbl.y, cbl.z, cbl.w, cbh.x, cbh.y, cbh.z, cbh.w};
  short8 o;
  #pragma unroll
  for (int j = 0; j < 8; ++j) {
    float4 w = cw4[d0 + j];
    float a = cbv[j];
    a = fmaf(b2f((u16)x3[j]), w.x, a);
    a = fmaf(b2f((u16)x2[j]), w.y, a);
    a = fmaf(b2f((u16)x1[j]), w.z, a);
    a = fmaf(b2f((u16)x0[j]), w.w, a);
    o[j] = (short)f2b(siluf_(a));
  }
  *(short8*)(xab + (size_t)token * DI + d0) = o;
}

// ---------------- chunked selective scan (bf16 state, f32x4 LDS reads) ----------------
__global__ __launch_bounds__(256) void scan_phase1(const u16* __restrict__ ub, const float* __restrict__ dec,
                                                   const float* __restrict__ Bm, u16* __restrict__ lend,
                                                   float* __restrict__ P) {
  __shared__ __align__(16) float dl[LCH * NST], bl[LCH * NST];
  int bid = blockIdx.x;
  int dblk = bid % 6, b = (bid / 6) % BATCH, c = bid / (6 * BATCH);
  int d = dblk * 256 + threadIdx.x;
  int t0 = c * LCH;
  size_t base16 = (size_t)(b * SEQ + t0) * NST;
  for (int i = threadIdx.x; i < LCH * NST / 4; i += 256) {
    ((float4*)dl)[i] = ((const float4*)(dec + base16))[i];
    ((float4*)bl)[i] = ((const float4*)(Bm + base16))[i];
  }
  __syncthreads();
  float h[NST];
  #pragma unroll
  for (int n = 0; n < NST; ++n) h[n] = 0.f;
  const u16* up = ub + (size_t)(b * SEQ + t0) * DI + d;
  for (int t = 0; t < LCH; ++t) {
    float uu = b2f(up[(size_t)t * DI]);
    const f32x4* d4 = (const f32x4*)(dl + t * NST);
    const f32x4* b4 = (const f32x4*)(bl + t * NST);
    #pragma unroll
    for (int q = 0; q < 4; ++q) {
      f32x4 dd = d4[q], bb = b4[q];
      #pragma unroll
      for (int j = 0; j < 4; ++j) h[q * 4 + j] = fmaf(h[q * 4 + j], dd[j], bb[j] * uu);
    }
  }
  u16* lo = lend + ((size_t)(c * BATCH + b) * DI + d) * NST;
  short8 s0, s1;
  #pragma unroll
  for (int n = 0; n < 8; ++n) { s0[n] = (short)f2b(h[n]); s1[n] = (short)f2b(h[8 + n]); }
  ((short8*)lo)[0] = s0;
  ((short8*)lo)[1] = s1;
  if (dblk == 0 && threadIdx.x < NST) {
    float pr = 1.f;
    for (int t = 0; t < LCH; ++t) pr *= dl[t * NST + threadIdx.x];
    P[(size_t)(c * BATCH + b) * NST + threadIdx.x] = pr;
  }
}

__global__ __launch_bounds__(256) void scan_phase2(const u16* __restrict__ lend, const float* __restrict__ P,
                                                   u16* __restrict__ Hin) {
  int flat = blockIdx.x * 256 + threadIdx.x;  // < BATCH*DI*NST
  int n = flat & 15;
  int d = (flat >> 4) % DI;
  int b = flat / (DI * NST);
  float h = 0.f;
  for (int c = 0; c < NCH; ++c) {
    size_t idx = ((size_t)(c * BATCH + b) * DI + d) * NST + n;
    Hin[idx] = f2b(h);
    h = fmaf(P[(size_t)(c * BATCH + b) * NST + n], h, b2f(lend[idx]));
  }
}

__global__ __launch_bounds__(256) void scan_phase3(const u16* __restrict__ ub, const float* __restrict__ dec,
                                                   const float* __restrict__ Bm, const float* __restrict__ Cm,
                                                   const u16* __restrict__ Hin, const u16* __restrict__ xpg,
                                                   u16* __restrict__ gy) {
  __shared__ __align__(16) float dl[LCH * NST], bl[LCH * NST], cl[LCH * NST];
  int bid = blockIdx.x;
  int dblk = bid % 6, b = (bid / 6) % BATCH, c = bid / (6 * BATCH);
  int d = dblk * 256 + threadIdx.x;
  int t0 = c * LCH;
  size_t base16 = (size_t)(b * SEQ + t0) * NST;
  for (int i = threadIdx.x; i < LCH * NST / 4; i += 256) {
    ((float4*)dl)[i] = ((const float4*)(dec + base16))[i];
    ((float4*)bl)[i] = ((const float4*)(Bm + base16))[i];
    ((float4*)cl)[i] = ((const float4*)(Cm + base16))[i];
  }
  __syncthreads();
  float h[NST];
  const short8* hi = (const short8*)(Hin + ((size_t)(c * BATCH + b) * DI + d) * NST);
  short8 h0 = hi[0], h1 = hi[1];
  #pragma unroll
  for (int n = 0; n < 8; ++n) { h[n] = b2f((u16)h0[n]); h[8 + n] = b2f((u16)h1[n]); }
  const u16* up = ub + (size_t)(b * SEQ + t0) * DI + d;
  const u16* gp = xpg + (size_t)(b * SEQ + t0) * NIG + DI + d;
  u16* yp = gy + (size_t)(b * SEQ + t0) * DI + d;
  for (int t = 0; t < LCH; ++t) {
    float uu = b2f(up[(size_t)t * DI]);
    const f32x4* d4 = (const f32x4*)(dl + t * NST);
    const f32x4* b4 = (const f32x4*)(bl + t * NST);
    const f32x4* c4 = (const f32x4*)(cl + t * NST);
    float acc = 0.f;
    #pragma unroll
    for (int q = 0; q < 4; ++q) {
      f32x4 dd = d4[q], bb = b4[q], cc = c4[q];
      #pragma unroll
      for (int j = 0; j < 4; ++j) {
        h[q * 4 + j] = fmaf(h[q * 4 + j], dd[j], bb[j] * uu);
        acc = fmaf(h[q * 4 + j], cc[j], acc);
      }
    }
    float g = b2f(gp[(size_t)t * NIG]);
    yp[(size_t)t * DI] = f2b(siluf_(g) * acc);
  }
}

extern "C" void kernel_launch(void* const* d_in, const int* in_sizes, int n_in,
                              void* d_out, int out_size, void* d_ws, size_t ws_size,
                              hipStream_t stream) {
  const float* x      = (const float*)d_in[0];
  const float* ln_g   = (const float*)d_in[1];
  const float* ln_b   = (const float*)d_in[2];
  const float* W_in   = (const float*)d_in[3];
  const float* b_in   = (const float*)d_in[4];
  const float* conv_w = (const float*)d_in[5];
  const float* conv_b = (const float*)d_in[6];
  const float* W_A    = (const float*)d_in[7];
  const float* b_A    = (const float*)d_in[8];
  const float* W_B    = (const float*)d_in[9];
  const float* b_B    = (const float*)d_in[10];
  const float* W_C    = (const float*)d_in[11];
  const float* b_C    = (const float*)d_in[12];
  const float* W_dt   = (const float*)d_in[13];
  const float* b_dt   = (const float*)d_in[14];
  const float* W_S    = (const float*)d_in[15];
  const float* b_S    = (const float*)d_in[16];
  const float* W_gate = (const float*)d_in[17];
  const float* b_gate = (const float*)d_in[18];
  const float* W_out  = (const float*)d_in[19];
  const float* b_out  = (const float*)d_in[20];
  float* out = (float*)d_out;

  char* p = (char*)d_ws;
  auto alloc = [&](size_t bytes) { char* r = p; p += (bytes + 255) & ~(size_t)255; return r; };
  u16*   Wigb    = (u16*)alloc((size_t)NIG * DM * 2);
  float* biasig  = (float*)alloc((size_t)NIG * 4);
  u16*   WSb     = (u16*)alloc((size_t)DI * DI * 2);
  u16*   Woutb   = (u16*)alloc((size_t)DM * DI * 2);
  u16*   Wabcd   = (u16*)alloc((size_t)64 * DI * 2);
  float* bias64  = (float*)alloc(64 * 4);
  u16*   xnb     = (u16*)alloc((size_t)NTOK * DM * 2);
  u16*   xpg     = (u16*)alloc((size_t)NTOK * NIG * 2);
  u16*   xab     = (u16*)alloc((size_t)NTOK * DI * 2);   // reused as gy
  u16*   ub      = (u16*)alloc((size_t)NTOK * DI * 2);
  float* Zp      = (float*)alloc((size_t)4 * NTOK * 64 * 4);
  float* decb    = (float*)alloc((size_t)NTOK * NST * 4);
  float* Bmb     = (float*)alloc((size_t)NTOK * NST * 4);
  float* Cmb     = (float*)alloc((size_t)NTOK * NST * 4);
  u16*   lend    = (u16*)alloc((size_t)NCH * BATCH * DI * NST * 2);
  u16*   Hin     = (u16*)alloc((size_t)NCH * BATCH * DI * NST * 2);
  float* P       = (float*)alloc((size_t)NCH * BATCH * NST * 4);
  u16* gy = xab;

  cast_all<<<(N_CAST + 255) / 256, 256, 0, stream>>>(W_in, W_gate, b_in, b_gate, W_S, W_out,
                                                     W_A, W_dt, W_B, W_C, b_A, b_dt, b_B, b_C,
                                                     Wigb, biasig, WSb, Woutb, Wabcd, bias64);

  ln_kernel<<<NTOK, 256, 0, stream>>>(x, ln_g, ln_b, xnb);

  // fused in|gate GEMM -> xpg bf16 (BM=128, BK=128: nk=6)
  gemm_bt<2, 128, 128><<<dim3(NIG / 128, NTOK / 128), 512, 0, stream>>>(xnb, Wigb, biasig, nullptr, nullptr,
                                                                        nullptr, xpg, NTOK, NIG, DM);

  conv_silu<<<NTOK * (DI / 8) / 256, 256, 0, stream>>>(xpg, conv_w, conv_b, xab);

  // S GEMM with fused u = xa * sigmoid(Sp) -> ub bf16 (BM=128, BK=128: nk=12)
  gemm_bt<1, 128, 128><<<dim3(DI / 128, NTOK / 128), 512, 0, stream>>>(xab, WSb, b_S, nullptr, xab,
                                                                       nullptr, ub, NTOK, DI, DI);

  gemm_abcd<<<dim3(NTOK / 64, 4), 256, 0, stream>>>(ub, Wabcd, Zp, NTOK, DI);
  abcd_combine<<<NTOK * 16 / 256, 256, 0, stream>>>(Zp, bias64, decb, Bmb, Cmb, NTOK);

  scan_phase1<<<NCH * BATCH * (DI / 256), 256, 0, stream>>>(ub, decb, Bmb, lend, P);
  scan_phase2<<<BATCH * DI * NST / 256, 256, 0, stream>>>(lend, P, Hin);
  scan_phase3<<<NCH * BATCH * (DI / 256), 256, 0, stream>>>(ub, decb, Bmb, Cmb, Hin, xpg, gy);

  // out GEMM + residual (f32 out): BM=64, BK=64: nk=24, 48KB -> 3 blocks/CU
  gemm_bt<0, 64, 64><<<dim3(DM / 128, NTOK / 64), 256, 0, stream>>>(gy, Woutb, b_out, x, nullptr,
                                                                    out, nullptr, NTOK, DM, DI);
}

// Round 21
// 184.710 us; speedup vs baseline: 1.1042x; 1.1042x over previous
//
#include <hip/hip_runtime.h>

// BayesianMambaBlock on MI355X (gfx950).  [Round-19 best config: BK=64 everywhere]
// LN -> fused (in|gate) GEMM [BM=128,BK=64] -> conv+silu -> S GEMM [BM=128,BK=64] (fused u) ->
// abcd GEMM split-K4 + combine -> chunked scan (bf16 state, f32x4 LDS reads, phase3 fused gate) ->
// out GEMM [BM=64,BK=64] (+resid, f32).
// gemm_bt<MODE,BM,BK>: tile BMx128, wave tile 32x64, 2 LDS buffers, vmcnt(0)+s_barrier per K-tile
// with next-tile stage issued one compute-phase ahead, setprio, CPR-chunk/row XOR LDS swizzle,
// XCD-aware block swizzle.

typedef unsigned short u16;
using short8 = __attribute__((ext_vector_type(8))) short;
using f32x4  = __attribute__((ext_vector_type(4))) float;

#define BATCH 2
#define SEQ   2048
#define DM    768
#define DI    1536
#define NIG   (2*DI)        // fused in+gate width 3072
#define NST   16
#define LCH   64
#define NCH   32
#define NTOK  (BATCH*SEQ)   // 4096

__device__ __forceinline__ u16 f2b(float x) {
  unsigned u = __float_as_uint(x);
  u += 0x7FFFu + ((u >> 16) & 1u);   // round-to-nearest-even bf16
  return (u16)(u >> 16);
}
__device__ __forceinline__ float b2f(u16 v) { return __uint_as_float((unsigned)v << 16); }
__device__ __forceinline__ float sigmoidf_(float x) { return 1.f / (1.f + expf(-x)); }
__device__ __forceinline__ float siluf_(float x) { return x / (1.f + expf(-x)); }

// ---------------- one-shot weight prep: all casts in a single launch ----------------
#define N_IG   (NIG * DM / 4)
#define N_WS   (DI * DI / 4)
#define N_WO   (DM * DI / 4)
#define N_WAB  (64 * DI / 4)
#define N_CAST (N_IG + N_WS + N_WO + N_WAB + NIG + 64)

__global__ __launch_bounds__(256) void cast_all(
    const float* __restrict__ Wi, const float* __restrict__ Wg,
    const float* __restrict__ bi, const float* __restrict__ bg,
    const float* __restrict__ WS, const float* __restrict__ WO,
    const float* __restrict__ WA, const float* __restrict__ Wdt,
    const float* __restrict__ WB, const float* __restrict__ WC,
    const float* __restrict__ bA, const float* __restrict__ bdt,
    const float* __restrict__ bB, const float* __restrict__ bC,
    u16* __restrict__ Wigb, float* __restrict__ biasig,
    u16* __restrict__ WSb, u16* __restrict__ Woutb,
    u16* __restrict__ Wabcd, float* __restrict__ bias64) {
  int i = blockIdx.x * 256 + threadIdx.x;
  if (i < N_IG) {
    int i4 = i * 4, r = i4 / DM, c = i4 % DM;
    const float* src = (r < DI) ? Wi + (size_t)r * DM + c : Wg + (size_t)(r - DI) * DM + c;
    float4 v = *(const float4*)src;
    ushort4 o; o.x = f2b(v.x); o.y = f2b(v.y); o.z = f2b(v.z); o.w = f2b(v.w);
    ((ushort4*)Wigb)[i] = o;
  } else if (i < N_IG + N_WS) {
    int j = i - N_IG;
    float4 v = ((const float4*)WS)[j];
    ushort4 o; o.x = f2b(v.x); o.y = f2b(v.y); o.z = f2b(v.z); o.w = f2b(v.w);
    ((ushort4*)WSb)[j] = o;
  } else if (i < N_IG + N_WS + N_WO) {
    int j = i - N_IG - N_WS;
    float4 v = ((const float4*)WO)[j];
    ushort4 o; o.x = f2b(v.x); o.y = f2b(v.y); o.z = f2b(v.z); o.w = f2b(v.w);
    ((ushort4*)Woutb)[j] = o;
  } else if (i < N_IG + N_WS + N_WO + N_WAB) {
    int j = i - N_IG - N_WS - N_WO;
    int i4 = j * 4, r = i4 / DI, c = i4 % DI;
    const float* src = (r < 16) ? WA + (size_t)r * DI
                     : (r < 32) ? Wdt + (size_t)(r - 16) * DI
                     : (r < 48) ? WB + (size_t)(r - 32) * DI
                                : WC + (size_t)(r - 48) * DI;
    float4 v = *(const float4*)(src + c);
    ushort4 o; o.x = f2b(v.x); o.y = f2b(v.y); o.z = f2b(v.z); o.w = f2b(v.w);
    ((ushort4*)Wabcd)[j] = o;
  } else if (i < N_IG + N_WS + N_WO + N_WAB + NIG) {
    int j = i - N_IG - N_WS - N_WO - N_WAB;
    biasig[j] = (j < DI) ? bi[j] : bg[j - DI];
  } else if (i < N_CAST) {
    int j = i - N_IG - N_WS - N_WO - N_WAB - NIG;
    bias64[j] = (j < 16) ? bA[j] : (j < 32) ? bdt[j - 16] : (j < 48) ? bB[j - 32] : bC[j - 48];
  }
}

// ---------------- LayerNorm -> bf16 ----------------
__global__ __launch_bounds__(256) void ln_kernel(const float* __restrict__ x, const float* __restrict__ g,
                                                 const float* __restrict__ bb, u16* __restrict__ xn) {
  int m = blockIdx.x, tid = threadIdx.x;
  const float* xr = x + (size_t)m * DM;
  float v0 = xr[tid], v1 = xr[tid + 256], v2 = xr[tid + 512];
  float s  = v0 + v1 + v2;
  float s2 = fmaf(v0, v0, fmaf(v1, v1, v2 * v2));
  #pragma unroll
  for (int off = 32; off > 0; off >>= 1) { s += __shfl_down(s, off); s2 += __shfl_down(s2, off); }
  __shared__ float sh[8];
  int wave = tid >> 6, lane = tid & 63;
  if (lane == 0) { sh[wave] = s; sh[4 + wave] = s2; }
  __syncthreads();
  float S1 = sh[0] + sh[1] + sh[2] + sh[3];
  float S2 = sh[4] + sh[5] + sh[6] + sh[7];
  float mu = S1 * (1.f / DM);
  float var = S2 * (1.f / DM) - mu * mu;
  float rs = rsqrtf(var + 1e-5f);
  u16* o = xn + (size_t)m * DM;
  o[tid]       = f2b((v0 - mu) * rs * g[tid]       + bb[tid]);
  o[tid + 256] = f2b((v1 - mu) * rs * g[tid + 256] + bb[tid + 256]);
  o[tid + 512] = f2b((v2 - mu) * rs * g[tid + 512] + bb[tid + 512]);
}

__device__ __forceinline__ void gll16(const void* g, void* l) {
  __builtin_amdgcn_global_load_lds((const __attribute__((address_space(1))) void*)g,
                                   (__attribute__((address_space(3))) void*)l, 16, 0, 0);
}

// ---------------- bf16 MFMA NT-GEMM: acc = A[M][K] * B[N][K]^T + bias ----------------
// BM=128: 512 thr/8 waves; BM=64: 256 thr/4 waves. Tile BMx128, wave tile 32x64, template BK.
// 2 LDS buffers; per K-tile: {vmcnt(0); s_barrier; STAGE(t+1); COMPUTE(t)}.
// Staging: CPR=BK/8 chunks/row; chunk c: row=c/CPR, slot c%CPR holds global k-octet
// (c%CPR)^(row%CPR). Read: k-octet q at slot q^(row%CPR).
// MODE 0: C f32 = acc + bias + aux(resid f32); MODE 1: Cb = bf16(b2f(auxb)*sigmoid(acc+bias));
// MODE 2: Cb = bf16(acc+bias)
template <int MODE, int BM, int BK>
__global__ __launch_bounds__(BM == 128 ? 512 : 256) void gemm_bt(
    const u16* __restrict__ A, const u16* __restrict__ B,
    const float* __restrict__ bias, const float* __restrict__ aux,
    const u16* __restrict__ auxb,
    float* __restrict__ C, u16* __restrict__ Cb,
    int M, int N, int K) {
  constexpr int NT   = (BM == 128 ? 512 : 256);
  constexpr int CPR  = BK / 8;           // 16B chunks per row
  constexpr int CM   = CPR - 1;
  constexpr int AU   = BM * CPR / NT;    // A staging units
  constexpr int BU   = 128 * CPR / NT;   // B staging units
  constexpr int RST  = NT / CPR;         // rows per unit (multiple of CPR)
  constexpr int NKK  = BK / 32;          // k-subtiles per K-tile
  __shared__ __align__(16) u16 As[2][BM * BK];
  __shared__ __align__(16) u16 Bs[2][128 * BK];
  const int tid = threadIdx.x, wave = tid >> 6, lane = tid & 63;

  // XCD-aware bijective swizzle (nwg % 8 == 0 for all our grids)
  const int nbx = gridDim.x, nwg = nbx * gridDim.y;
  const int orig = blockIdx.y * nbx + blockIdx.x;
  const int cpx = nwg >> 3;
  const int swz = (orig & 7) * cpx + (orig >> 3);
  const int m0 = (swz / nbx) * BM, n0 = (swz % nbx) * 128;

  const int wm = (wave >> 1) * 32, wn = (wave & 1) * 64;
  const int fr = lane & 15, fq = lane >> 4;
  f32x4 acc[2][4] = {};

  // staging base for chunk c = tid: row = tid/CPR, k-octet (tid%CPR)^(row%CPR)
  const int srow = tid / CPR;
  const u16* Ag0 = A + (size_t)(m0 + srow) * K + (((tid & CM) ^ (srow & CM))) * 8;
  const u16* Bg0 = B + (size_t)(n0 + srow) * K + (((tid & CM) ^ (srow & CM))) * 8;
  const int lbase = (wave * 64) * 8;   // wave-uniform; HW adds lane*16B
  const int lstep = NT * 8;            // u16 per unit

  // ds_read offsets (u16): row r, k-octet q = kk*4+fq at slot q^(r&CM)
  int offA[NKK][2], offB[NKK][4];
  #pragma unroll
  for (int kk = 0; kk < NKK; ++kk) {
    #pragma unroll
    for (int i = 0; i < 2; ++i) {
      int ra = wm + i * 16 + fr;
      offA[kk][i] = ra * BK + (((kk * 4 + fq) ^ (ra & CM))) * 8;
    }
    #pragma unroll
    for (int i = 0; i < 4; ++i) {
      int rb = wn + i * 16 + fr;
      offB[kk][i] = rb * BK + (((kk * 4 + fq) ^ (rb & CM))) * 8;
    }
  }

  const int nk = K / BK;

#define STAGE_BT(tt) { const int bb_ = (tt) & 1; const int ko_ = (tt) * BK; \
    _Pragma("unroll") for (int u = 0; u < AU; ++u) \
      gll16(Ag0 + (size_t)u * RST * K + ko_, (u16*)As[bb_] + u * lstep + lbase); \
    _Pragma("unroll") for (int u = 0; u < BU; ++u) \
      gll16(Bg0 + (size_t)u * RST * K + ko_, (u16*)Bs[bb_] + u * lstep + lbase); }
#define COMPUTE_BT(tt) { const u16* as_ = As[(tt) & 1]; const u16* bs_ = Bs[(tt) & 1]; \
    _Pragma("unroll") for (int kk = 0; kk < NKK; ++kk) { \
      short8 av[2], bv[4]; \
      _Pragma("unroll") for (int i = 0; i < 2; ++i) av[i] = *(const short8*)(as_ + offA[kk][i]); \
      _Pragma("unroll") for (int i = 0; i < 4; ++i) bv[i] = *(const short8*)(bs_ + offB[kk][i]); \
      __builtin_amdgcn_s_setprio(1); \
      _Pragma("unroll") for (int mi = 0; mi < 2; ++mi) \
        _Pragma("unroll") for (int ni = 0; ni < 4; ++ni) \
          acc[mi][ni] = __builtin_amdgcn_mfma_f32_16x16x32_bf16(av[mi], bv[ni], acc[mi][ni], 0, 0, 0); \
      __builtin_amdgcn_s_setprio(0); } }

  STAGE_BT(0);
  for (int t = 0; t < nk; ++t) {
    asm volatile("s_waitcnt vmcnt(0)" ::: "memory");   // tile t landed (issued 1 compute phase ago)
    __builtin_amdgcn_s_barrier();                      // publishes tile t; retires reads of buf (t+1)&1
    if (t + 1 < nk) STAGE_BT(t + 1);
    COMPUTE_BT(t);
  }
#undef STAGE_BT
#undef COMPUTE_BT

  #pragma unroll
  for (int ni = 0; ni < 4; ++ni) {
    int col = n0 + wn + ni * 16 + fr;
    float bv_ = bias[col];
    #pragma unroll
    for (int mi = 0; mi < 2; ++mi) {
      int row = m0 + wm + mi * 16 + fq * 4;
      #pragma unroll
      for (int j = 0; j < 4; ++j) {
        size_t off = (size_t)(row + j) * N + col;
        float z = acc[mi][ni][j] + bv_;
        if (MODE == 0) {
          C[off] = z + aux[off];
        } else if (MODE == 1) {
          Cb[off] = f2b(b2f(auxb[off]) * sigmoidf_(z));
        } else {
          Cb[off] = f2b(z);
        }
      }
    }
  }
}

// ---------------- abcd GEMM split-K: Zp[ks] = ub[M][Kq] * Wabcd[64][Kq]^T ----------------
__global__ __launch_bounds__(256) void gemm_abcd(const u16* __restrict__ A, const u16* __restrict__ B,
                                                 float* __restrict__ Zp, int M, int K) {
  __shared__ __align__(16) u16 As[2][64 * 64];
  __shared__ __align__(16) u16 Bs[2][64 * 64];
  const int tid = threadIdx.x, wave = tid >> 6, lane = tid & 63;
  const int m0 = blockIdx.x * 64;
  const int ks = blockIdx.y;
  const int Kq = K >> 2;            // 384
  const int kbase = ks * Kq;
  const int wm = wave * 16;
  const int fr = lane & 15, fq = lane >> 4;
  f32x4 acc[4] = {};

  const int c0 = tid, c1 = tid + 256;
  const u16* Ag0 = A + (size_t)(m0 + (c0 >> 3)) * K + kbase + ((c0 & 7) ^ ((c0 >> 3) & 7)) * 8;
  const u16* Ag1 = A + (size_t)(m0 + (c1 >> 3)) * K + kbase + ((c1 & 7) ^ ((c1 >> 3) & 7)) * 8;
  const u16* Bg0 = B + (size_t)(c0 >> 3) * K + kbase + ((c0 & 7) ^ ((c0 >> 3) & 7)) * 8;
  const u16* Bg1 = B + (size_t)(c1 >> 3) * K + kbase + ((c1 & 7) ^ ((c1 >> 3) & 7)) * 8;
  const int lo0 = (wave * 64) * 8;
  const int lo1 = (256 + wave * 64) * 8;

  int offAv[2], offBv[2][4];
  {
    int r = wm + fr;
    #pragma unroll
    for (int kk = 0; kk < 2; ++kk) offAv[kk] = r * 64 + ((kk * 4 + fq) ^ (r & 7)) * 8;
    #pragma unroll
    for (int i = 0; i < 4; ++i) {
      int rb = i * 16 + fr;
      #pragma unroll
      for (int kk = 0; kk < 2; ++kk) offBv[kk][i] = rb * 64 + ((kk * 4 + fq) ^ (rb & 7)) * 8;
    }
  }

  const int nk = Kq >> 6;   // 6
  gll16(Ag0, (u16*)As[0] + lo0);
  gll16(Ag1, (u16*)As[0] + lo1);
  gll16(Bg0, (u16*)Bs[0] + lo0);
  gll16(Bg1, (u16*)Bs[0] + lo1);

  for (int t = 0; t < nk; ++t) {
    __syncthreads();
    if (t + 1 < nk) {
      int ko = (t + 1) * 64;
      gll16(Ag0 + ko, (u16*)As[(t + 1) & 1] + lo0);
      gll16(Ag1 + ko, (u16*)As[(t + 1) & 1] + lo1);
      gll16(Bg0 + ko, (u16*)Bs[(t + 1) & 1] + lo0);
      gll16(Bg1 + ko, (u16*)Bs[(t + 1) & 1] + lo1);
    }
    const u16* as = As[t & 1];
    const u16* bs = Bs[t & 1];
    #pragma unroll
    for (int kk = 0; kk < 2; ++kk) {
      short8 av = *(const short8*)(as + offAv[kk]);
      short8 bv[4];
      #pragma unroll
      for (int i = 0; i < 4; ++i) bv[i] = *(const short8*)(bs + offBv[kk][i]);
      #pragma unroll
      for (int ni = 0; ni < 4; ++ni)
        acc[ni] = __builtin_amdgcn_mfma_f32_16x16x32_bf16(av, bv[ni], acc[ni], 0, 0, 0);
    }
  }

  float* zp = Zp + (size_t)ks * M * 64;
  #pragma unroll
  for (int ni = 0; ni < 4; ++ni) {
    int col = ni * 16 + fr;
    #pragma unroll
    for (int j = 0; j < 4; ++j) {
      int row = m0 + wm + fq * 4 + j;
      zp[(size_t)row * 64 + col] = acc[ni][j];
    }
  }
}

// combine split-K partials; fused dec/Bm/Cm epilogue
__global__ __launch_bounds__(256) void abcd_combine(const float* __restrict__ Zp, const float* __restrict__ bias64,
                                                    float* __restrict__ dec, float* __restrict__ Bm,
                                                    float* __restrict__ Cm, int M) {
  int idx = blockIdx.x * 256 + threadIdx.x;  // < M*16
  int row = idx >> 4, n = idx & 15;
  float zA = bias64[n], zDt = bias64[16 + n], zB = bias64[32 + n], zC = bias64[48 + n];
  #pragma unroll
  for (int ks = 0; ks < 4; ++ks) {
    const float* zp = Zp + ((size_t)ks * M + row) * 64;
    zA += zp[n]; zDt += zp[16 + n]; zB += zp[32 + n]; zC += zp[48 + n];
  }
  size_t o = (size_t)row * NST + n;
  dec[o] = expf(-expf(zA + zDt));
  Bm[o] = zB;
  Cm[o] = zC;
}

// ---------------- depthwise causal conv (k=4) + bias + silu; short8-vectorized ----------------
__global__ __launch_bounds__(256) void conv_silu(const u16* __restrict__ xpg, const float* __restrict__ cw,
                                                 const float* __restrict__ cb, u16* __restrict__ xab) {
  int idx = blockIdx.x * 256 + threadIdx.x;   // < NTOK*DI/8
  int d8 = idx % (DI / 8);
  int token = idx / (DI / 8);
  int t = token % SEQ;
  int d0 = d8 * 8;
  const short8* xv = (const short8*)(xpg + (size_t)token * NIG + d0);
  short8 z8 = {0, 0, 0, 0, 0, 0, 0, 0};
  short8 x3 = (t >= 3) ? xv[-3 * (NIG / 8)] : z8;
  short8 x2 = (t >= 2) ? xv[-2 * (NIG / 8)] : z8;
  short8 x1 = (t >= 1) ? xv[-1 * (NIG / 8)] : z8;
  short8 x0 = xv[0];
  const float4* cw4 = (const float4*)cw;
  float4 cbl = ((const float4*)cb)[d8 * 2], cbh = ((const float4*)cb)[d8 * 2 + 1];
  float cbv[8] = {cbl.x, cbl.y, cbl.z, cbl.w, cbh.x, cbh.y, cbh.z, cbh.w};
  short8 o;
  #pragma unroll
  for (int j = 0; j < 8; ++j) {
    float4 w = cw4[d0 + j];
    float a = cbv[j];
    a = fmaf(b2f((u16)x3[j]), w.x, a);
    a = fmaf(b2f((u16)x2[j]), w.y, a);
    a = fmaf(b2f((u16)x1[j]), w.z, a);
    a = fmaf(b2f((u16)x0[j]), w.w, a);
    o[j] = (short)f2b(siluf_(a));
  }
  *(short8*)(xab + (size_t)token * DI + d0) = o;
}

// ---------------- chunked selective scan (bf16 state, f32x4 LDS reads) ----------------
__global__ __launch_bounds__(256) void scan_phase1(const u16* __restrict__ ub, const float* __restrict__ dec,
                                                   const float* __restrict__ Bm, u16* __restrict__ lend,
                                                   float* __restrict__ P) {
  __shared__ __align__(16) float dl[LCH * NST], bl[LCH * NST];
  int bid = blockIdx.x;
  int dblk = bid % 6, b = (bid / 6) % BATCH, c = bid / (6 * BATCH);
  int d = dblk * 256 + threadIdx.x;
  int t0 = c * LCH;
  size_t base16 = (size_t)(b * SEQ + t0) * NST;
  for (int i = threadIdx.x; i < LCH * NST / 4; i += 256) {
    ((float4*)dl)[i] = ((const float4*)(dec + base16))[i];
    ((float4*)bl)[i] = ((const float4*)(Bm + base16))[i];
  }
  __syncthreads();
  float h[NST];
  #pragma unroll
  for (int n = 0; n < NST; ++n) h[n] = 0.f;
  const u16* up = ub + (size_t)(b * SEQ + t0) * DI + d;
  for (int t = 0; t < LCH; ++t) {
    float uu = b2f(up[(size_t)t * DI]);
    const f32x4* d4 = (const f32x4*)(dl + t * NST);
    const f32x4* b4 = (const f32x4*)(bl + t * NST);
    #pragma unroll
    for (int q = 0; q < 4; ++q) {
      f32x4 dd = d4[q], bb = b4[q];
      #pragma unroll
      for (int j = 0; j < 4; ++j) h[q * 4 + j] = fmaf(h[q * 4 + j], dd[j], bb[j] * uu);
    }
  }
  u16* lo = lend + ((size_t)(c * BATCH + b) * DI + d) * NST;
  short8 s0, s1;
  #pragma unroll
  for (int n = 0; n < 8; ++n) { s0[n] = (short)f2b(h[n]); s1[n] = (short)f2b(h[8 + n]); }
  ((short8*)lo)[0] = s0;
  ((short8*)lo)[1] = s1;
  if (dblk == 0 && threadIdx.x < NST) {
    float pr = 1.f;
    for (int t = 0; t < LCH; ++t) pr *= dl[t * NST + threadIdx.x];
    P[(size_t)(c * BATCH + b) * NST + threadIdx.x] = pr;
  }
}

__global__ __launch_bounds__(256) void scan_phase2(const u16* __restrict__ lend, const float* __restrict__ P,
                                                   u16* __restrict__ Hin) {
  int flat = blockIdx.x * 256 + threadIdx.x;  // < BATCH*DI*NST
  int n = flat & 15;
  int d = (flat >> 4) % DI;
  int b = flat / (DI * NST);
  float h = 0.f;
  for (int c = 0; c < NCH; ++c) {
    size_t idx = ((size_t)(c * BATCH + b) * DI + d) * NST + n;
    Hin[idx] = f2b(h);
    h = fmaf(P[(size_t)(c * BATCH + b) * NST + n], h, b2f(lend[idx]));
  }
}

__global__ __launch_bounds__(256) void scan_phase3(const u16* __restrict__ ub, const float* __restrict__ dec,
                                                   const float* __restrict__ Bm, const float* __restrict__ Cm,
                                                   const u16* __restrict__ Hin, const u16* __restrict__ xpg,
                                                   u16* __restrict__ gy) {
  __shared__ __align__(16) float dl[LCH * NST], bl[LCH * NST], cl[LCH * NST];
  int bid = blockIdx.x;
  int dblk = bid % 6, b = (bid / 6) % BATCH, c = bid / (6 * BATCH);
  int d = dblk * 256 + threadIdx.x;
  int t0 = c * LCH;
  size_t base16 = (size_t)(b * SEQ + t0) * NST;
  for (int i = threadIdx.x; i < LCH * NST / 4; i += 256) {
    ((float4*)dl)[i] = ((const float4*)(dec + base16))[i];
    ((float4*)bl)[i] = ((const float4*)(Bm + base16))[i];
    ((float4*)cl)[i] = ((const float4*)(Cm + base16))[i];
  }
  __syncthreads();
  float h[NST];
  const short8* hi = (const short8*)(Hin + ((size_t)(c * BATCH + b) * DI + d) * NST);
  short8 h0 = hi[0], h1 = hi[1];
  #pragma unroll
  for (int n = 0; n < 8; ++n) { h[n] = b2f((u16)h0[n]); h[8 + n] = b2f((u16)h1[n]); }
  const u16* up = ub + (size_t)(b * SEQ + t0) * DI + d;
  const u16* gp = xpg + (size_t)(b * SEQ + t0) * NIG + DI + d;
  u16* yp = gy + (size_t)(b * SEQ + t0) * DI + d;
  for (int t = 0; t < LCH; ++t) {
    float uu = b2f(up[(size_t)t * DI]);
    const f32x4* d4 = (const f32x4*)(dl + t * NST);
    const f32x4* b4 = (const f32x4*)(bl + t * NST);
    const f32x4* c4 = (const f32x4*)(cl + t * NST);
    float acc = 0.f;
    #pragma unroll
    for (int q = 0; q < 4; ++q) {
      f32x4 dd = d4[q], bb = b4[q], cc = c4[q];
      #pragma unroll
      for (int j = 0; j < 4; ++j) {
        h[q * 4 + j] = fmaf(h[q * 4 + j], dd[j], bb[j] * uu);
        acc = fmaf(h[q * 4 + j], cc[j], acc);
      }
    }
    float g = b2f(gp[(size_t)t * NIG]);
    yp[(size_t)t * DI] = f2b(siluf_(g) * acc);
  }
}

extern "C" void kernel_launch(void* const* d_in, const int* in_sizes, int n_in,
                              void* d_out, int out_size, void* d_ws, size_t ws_size,
                              hipStream_t stream) {
  const float* x      = (const float*)d_in[0];
  const float* ln_g   = (const float*)d_in[1];
  const float* ln_b   = (const float*)d_in[2];
  const float* W_in   = (const float*)d_in[3];
  const float* b_in   = (const float*)d_in[4];
  const float* conv_w = (const float*)d_in[5];
  const float* conv_b = (const float*)d_in[6];
  const float* W_A    = (const float*)d_in[7];
  const float* b_A    = (const float*)d_in[8];
  const float* W_B    = (const float*)d_in[9];
  const float* b_B    = (const float*)d_in[10];
  const float* W_C    = (const float*)d_in[11];
  const float* b_C    = (const float*)d_in[12];
  const float* W_dt   = (const float*)d_in[13];
  const float* b_dt   = (const float*)d_in[14];
  const float* W_S    = (const float*)d_in[15];
  const float* b_S    = (const float*)d_in[16];
  const float* W_gate = (const float*)d_in[17];
  const float* b_gate = (const float*)d_in[18];
  const float* W_out  = (const float*)d_in[19];
  const float* b_out  = (const float*)d_in[20];
  float* out = (float*)d_out;

  char* p = (char*)d_ws;
  auto alloc = [&](size_t bytes) { char* r = p; p += (bytes + 255) & ~(size_t)255; return r; };
  u16*   Wigb    = (u16*)alloc((size_t)NIG * DM * 2);
  float* biasig  = (float*)alloc((size_t)NIG * 4);
  u16*   WSb     = (u16*)alloc((size_t)DI * DI * 2);
  u16*   Woutb   = (u16*)alloc((size_t)DM * DI * 2);
  u16*   Wabcd   = (u16*)alloc((size_t)64 * DI * 2);
  float* bias64  = (float*)alloc(64 * 4);
  u16*   xnb     = (u16*)alloc((size_t)NTOK * DM * 2);
  u16*   xpg     = (u16*)alloc((size_t)NTOK * NIG * 2);
  u16*   xab     = (u16*)alloc((size_t)NTOK * DI * 2);   // reused as gy
  u16*   ub      = (u16*)alloc((size_t)NTOK * DI * 2);
  float* Zp      = (float*)alloc((size_t)4 * NTOK * 64 * 4);
  float* decb    = (float*)alloc((size_t)NTOK * NST * 4);
  float* Bmb     = (float*)alloc((size_t)NTOK * NST * 4);
  float* Cmb     = (float*)alloc((size_t)NTOK * NST * 4);
  u16*   lend    = (u16*)alloc((size_t)NCH * BATCH * DI * NST * 2);
  u16*   Hin     = (u16*)alloc((size_t)NCH * BATCH * DI * NST * 2);
  float* P       = (float*)alloc((size_t)NCH * BATCH * NST * 4);
  u16* gy = xab;

  cast_all<<<(N_CAST + 255) / 256, 256, 0, stream>>>(W_in, W_gate, b_in, b_gate, W_S, W_out,
                                                     W_A, W_dt, W_B, W_C, b_A, b_dt, b_B, b_C,
                                                     Wigb, biasig, WSb, Woutb, Wabcd, bias64);

  ln_kernel<<<NTOK, 256, 0, stream>>>(x, ln_g, ln_b, xnb);

  // fused in|gate GEMM -> xpg bf16 (BM=128, BK=64: nk=12)
  gemm_bt<2, 128, 64><<<dim3(NIG / 128, NTOK / 128), 512, 0, stream>>>(xnb, Wigb, biasig, nullptr, nullptr,
                                                                       nullptr, xpg, NTOK, NIG, DM);

  conv_silu<<<NTOK * (DI / 8) / 256, 256, 0, stream>>>(xpg, conv_w, conv_b, xab);

  // S GEMM with fused u = xa * sigmoid(Sp) -> ub bf16 (BM=128, BK=64: nk=24)
  gemm_bt<1, 128, 64><<<dim3(DI / 128, NTOK / 128), 512, 0, stream>>>(xab, WSb, b_S, nullptr, xab,
                                                                      nullptr, ub, NTOK, DI, DI);

  gemm_abcd<<<dim3(NTOK / 64, 4), 256, 0, stream>>>(ub, Wabcd, Zp, NTOK, DI);
  abcd_combine<<<NTOK * 16 / 256, 256, 0, stream>>>(Zp, bias64, decb, Bmb, Cmb, NTOK);

  scan_phase1<<<NCH * BATCH * (DI / 256), 256, 0, stream>>>(ub, decb, Bmb, lend, P);
  scan_phase2<<<BATCH * DI * NST / 256, 256, 0, stream>>>(lend, P, Hin);
  scan_phase3<<<NCH * BATCH * (DI / 256), 256, 0, stream>>>(ub, decb, Bmb, Cmb, Hin, xpg, gy);

  // out GEMM + residual (f32 out): BM=64, BK=64: nk=24, 48KB -> 3 blocks/CU
  gemm_bt<0, 64, 64><<<dim3(DM / 128, NTOK / 64), 256, 0, stream>>>(gy, Woutb, b_out, x, nullptr,
                                                                    out, nullptr, NTOK, DM, DI);
}